// Round 28
// baseline (70.824 us; speedup 1.0000x reference)
//
#include <hip/hip_runtime.h>
#include <hip/hip_bf16.h>

typedef _Float16 f16x8 __attribute__((ext_vector_type(8)));
typedef float f32x4 __attribute__((ext_vector_type(4)));

#define BM 128      // rows per block
#define NCHUNK 32   // 3072 / 96 ; chunk = 8 features = 96 K-halves
#define IN_F 256
#define OUT_F 256
#define KDIM 3072   // 256 * 12
// frag-order: one "group" = 512 halves = 64 lanes x 8 halves (1 KB)
// A (LDS dbuf): 24 groups ; B (LDS dbuf): 48 groups
// W2F global layout = chunk-major frag order: chunk c -> 48 contiguous groups
// waves 0..7: producers (stageB + produce). waves 8..15: consumers (MFMA, prio-boosted).

__device__ inline void async_b16(const void* g, void* l) {
  __builtin_amdgcn_global_load_lds(
      (const __attribute__((address_space(1))) unsigned int*)g,
      (__attribute__((address_space(3))) unsigned int*)l, 16, 0, 0);
}

static __device__ inline unsigned pack2(float a, float b) {
  union { _Float16 h[2]; unsigned u; } t;
  t.h[0] = (_Float16)a;
  t.h[1] = (_Float16)b;
  return t.u;
}

// W2F unit u (16B = 8 halves): c=u/3072, r=u%3072, bcb=r/192, r2=r%192,
// g=r2/64, lane=r2%64 ; col o = bcb*16+(lane&15), k8 = g*4+(lane>>4),
// k-halves = c*96 + k8*8 .. +7 ; k=i*12+m -> m<11: coeff[o][i][m], m==11: base_w[o][i]
__global__ __launch_bounds__(256) void prep_w(const float* __restrict__ coeff,
                                              const float* __restrict__ base_w,
                                              _Float16* __restrict__ W2F) {
  const int u   = blockIdx.x * 256 + threadIdx.x;   // 384*256 = 98304 units
  const int c   = u / 3072;
  const int r   = u % 3072;
  const int bcb = r / 192;
  const int r2  = r % 192;
  const int g   = r2 / 64;
  const int ln  = r2 % 64;
  const int o   = bcb * 16 + (ln & 15);
  const int k8  = g * 4 + (ln >> 4);
  const int kh0 = c * 96 + k8 * 8;
  _Float16 h[8];
  #pragma unroll
  for (int e = 0; e < 8; ++e) {
    const int k = kh0 + e;
    const int i = k / 12, m = k % 12;
    const float v = (m == 11) ? base_w[o * IN_F + i] : coeff[(o * IN_F + i) * 11 + m];
    h[e] = (_Float16)v;
  }
  *(f16x8*)&W2F[(size_t)u * 8] = *(const f16x8*)h;
}

__global__ __launch_bounds__(1024, 4) void kan_fused(const float* __restrict__ x,
                                                     const float* __restrict__ gamma,
                                                     const float* __restrict__ beta,
                                                     const _Float16* __restrict__ W2F,
                                                     float* __restrict__ out) {
  __shared__ _Float16 A0[24 * 512], A1[24 * 512];   // 24 KB each
  __shared__ _Float16 B0[48 * 512], B1[48 * 512];   // 48 KB each
  __shared__ float mu_s[BM], rs_s[BM];

  const int tid  = threadIdx.x;
  const int lane = tid & 63;
  const int wid  = tid >> 6;          // 0..15
  const int row0 = blockIdx.x * BM;

  const bool isprod = (wid < 8);

  // consumer roles (waves 8..15): wr = row half, wc = col group; 64x64 tiles
  const int wr   = (wid >> 2) & 1;
  const int wc   = wid & 3;
  const int lrow = lane & 15;

  f32x4 acc[4][4] = {};

  // producer map (waves 0..7):
  const int plrow = tid & 15;
  const int pfq   = (tid >> 4) & 3;   // feature-pair within chunk
  const int prb   = (tid >> 6) & 7;   // row block 0..7
  const int prow  = prb * 16 + plrow; // 0..127
  const float* xrow = x + (size_t)(row0 + prow) * IN_F + pfq * 2;
  const float* grow = gamma + pfq * 2;
  const float* brow = beta + pfq * 2;

  // producer dest offsets (halves), one per 8-half group k8 = pfq*3 + j
  int aoff0, aoff1, aoff2;
  {
    const int k80 = pfq * 3 + 0, k81 = pfq * 3 + 1, k82 = pfq * 3 + 2;
    aoff0 = (prb * 3 + (k80 >> 2)) * 512 + (k80 & 3) * 128 + plrow * 8;
    aoff1 = (prb * 3 + (k81 >> 2)) * 512 + (k81 & 3) * 128 + plrow * 8;
    aoff2 = (prb * 3 + (k82 >> 2)) * 512 + (k82 & 3) * 128 + plrow * 8;
  }

  // B staging via async DMA: producer wave w stages groups w*6 .. w*6+5
  const char* const wsrc = (const char*)W2F + (size_t)(wid & 7) * 6144 + (size_t)lane * 16;
  auto stageB = [&](int c, _Float16* Bb) {
    const char* gb = wsrc + (size_t)c * 49152;
    char* lb = (char*)Bb + (wid & 7) * 6144;
    #pragma unroll
    for (int j = 0; j < 6; ++j)
      async_b16(gb + j * 1024, lb + j * 1024);
  };

  // ---- prologue part 1 (T14 issue-early): producers launch DMA + prefetch
  float2 xv0 = {}, gv0 = {}, bv0 = {}, xv1 = {}, gv1 = {}, bv1 = {};
  if (isprod) {
    stageB(0, B0);                    // DMA latency hides under the LN pass
    xv0 = *(const float2*)(xrow);
    gv0 = *(const float2*)(grow);
    bv0 = *(const float2*)(brow);
    xv1 = *(const float2*)(xrow + 8);
    gv1 = *(const float2*)(grow + 8);
    bv1 = *(const float2*)(brow + 8);
  }

  // ---- LN stats, 8 lanes per row (parallel): all 128 rows in one pass ----
  {
    const int g  = lane >> 3;         // row group within wave: 0..7
    const int sl = lane & 7;          // sub-lane within row
    const int rr = wid * 8 + g;       // 0..127
    const float* rp = x + (size_t)(row0 + rr) * IN_F + sl * 4;
    float s = 0.0f, sq = 0.0f;
    #pragma unroll
    for (int j = 0; j < 8; ++j) {     // 8 independent float4 loads
      const float4 v = *(const float4*)(rp + j * 32);
      s  += v.x + v.y + v.z + v.w;
      sq += v.x * v.x + v.y * v.y + v.z * v.z + v.w * v.w;
    }
    #pragma unroll
    for (int off = 4; off >= 1; off >>= 1) {
      s  += __shfl_xor(s, off);
      sq += __shfl_xor(sq, off);
    }
    if (sl == 0) {
      const float mu  = s * (1.0f / 256.0f);
      const float var = sq * (1.0f / 256.0f) - mu * mu;
      mu_s[rr] = mu;
      rs_s[rr] = 1.0f / sqrtf(var + 1e-5f);
    }
  }
  __syncthreads();                    // stats visible + B(0) DMA drained

  float mu = 0.0f, rs = 0.0f;
  if (isprod) { mu = mu_s[prow]; rs = rs_s[prow]; }

  // two-stage register window-placement produce
  auto produce = [&](_Float16* buf, float2 xv, float2 gv, float2 bv) {
    unsigned R[12];
    #pragma unroll
    for (int q = 0; q < 2; ++q) {
      const float xr = q ? xv.y : xv.x;
      const float gq = q ? gv.y : gv.x;
      const float bq = q ? bv.y : bv.x;
      const float n  = (xr - mu) * rs * gq + bq;
      const float v  = (n + 1.75f) * 4.0f;      // knots t_j = -1.75 + 0.25*j
      const float fj = floorf(v);
      const float u  = v - fj;
      const float u2 = u * u, u3 = u2 * u;
      const float w0 = (1.0f / 6.0f) * (1.0f - 3.0f * u + 3.0f * u2 - u3);
      const float w1 = (1.0f / 6.0f) * (3.0f * u3 - 6.0f * u2 + 4.0f);
      const float w2 = (1.0f / 6.0f) * (-3.0f * u3 + 3.0f * u2 + 3.0f * u + 1.0f);
      const float w3 = (1.0f / 6.0f) * u3;
      const unsigned W0 = pack2(w0, w1);
      const unsigned W1 = pack2(w2, w3);
      const int p    = (int)fj - 3;             // window start half
      const bool odd = (p & 1);
      const unsigned v0 = odd ? (W0 << 16) : W0;
      const unsigned v1 = odd ? ((W0 >> 16) | (W1 << 16)) : W1;
      const unsigned v2 = odd ? (W1 >> 16) : 0u;
      const int s0 = (v >= 0.0f && v < 14.0f) ? (p >> 1) : 99;  // OOB -> all drop
      const int s1 = s0 + 1, s2 = s0 + 2;
      #pragma unroll
      for (int k = 0; k < 6; ++k) {
        unsigned r = (k == s0) ? v0 : 0u;
        r = (k == s1) ? v1 : r;
        r = (k == s2) ? v2 : r;
        R[q * 6 + k] = r;
      }
      const float sl2 = xr * __builtin_amdgcn_rcpf(1.0f + __expf(-xr));  // silu(raw x)
      // half 11 of the field = word 5 high half (also kills j=12/13 overhang)
      R[q * 6 + 5] = (R[q * 6 + 5] & 0x0000FFFFu) | pack2(0.0f, sl2);
    }
    *(f16x8*)&buf[aoff0] = *(const f16x8*)&R[0];
    *(f16x8*)&buf[aoff1] = *(const f16x8*)&R[4];
    *(f16x8*)&buf[aoff2] = *(const f16x8*)&R[8];
  };

  auto domfma = [&](const _Float16* Ab, const _Float16* Bb) {
    __builtin_amdgcn_s_setprio(1);    // T5: consumer MFMA waves win issue arbitration
    // preload ALL 12 A-frags (24 VGPRs) -> deep LDS-load pipeline, only B reads
    // remain on the per-fk critical path
    f16x8 a[3][4];
    #pragma unroll
    for (int fk = 0; fk < 3; ++fk)
      #pragma unroll
      for (int fm = 0; fm < 4; ++fm)
        a[fk][fm] = *(const f16x8*)&Ab[((wr * 4 + fm) * 3 + fk) * 512 + lane * 8];
    #pragma unroll
    for (int fk = 0; fk < 3; ++fk) {
      f16x8 b[4];
      #pragma unroll
      for (int fn = 0; fn < 4; ++fn)
        b[fn] = *(const f16x8*)&Bb[((wc * 4 + fn) * 3 + fk) * 512 + lane * 8];
      #pragma unroll
      for (int fm = 0; fm < 4; ++fm)
        #pragma unroll
        for (int fn = 0; fn < 4; ++fn)
          acc[fm][fn] = __builtin_amdgcn_mfma_f32_16x16x32_f16(a[fk][fm], b[fn], acc[fm][fn], 0, 0, 0);
    }
    __builtin_amdgcn_s_setprio(0);
  };

  // prologue part 2: produce A(0)
  if (isprod) produce(A0, xv0, gv0, bv0);
  __syncthreads();                    // A(0) visible

  for (int c = 0; c < NCHUNK; c += 2) {
    const int cp2 = (c + 2 < NCHUNK) ? (c + 2) : (NCHUNK - 1);
    const int cp3 = (c + 3 < NCHUNK) ? (c + 3) : (NCHUNK - 1);
    // interval even: consumers eat {A0,B0}=c ; producers build {A1,B1}=c+1
    if (isprod) {
      stageB(c + 1, B1);
      xv0 = *(const float2*)(xrow + cp2 * 8);
      gv0 = *(const float2*)(grow + cp2 * 8);
      bv0 = *(const float2*)(brow + cp2 * 8);
      produce(A1, xv1, gv1, bv1);
    } else {
      domfma(A0, B0);
    }
    __syncthreads();
    // interval odd: consumers eat {A1,B1}=c+1 ; producers build {A0,B0}=c+2
    if (isprod) {
      if (c + 2 < NCHUNK) {
        stageB(cp2, B0);
        xv1 = *(const float2*)(xrow + cp3 * 8);
        gv1 = *(const float2*)(grow + cp3 * 8);
        bv1 = *(const float2*)(brow + cp3 * 8);
        produce(A0, xv0, gv0, bv0);
      }
    } else {
      domfma(A1, B1);
    }
    __syncthreads();
  }

  // ---- epilogue (consumers only): col = lane&15, row = (lane>>4)*4 + r ----
  if (!isprod) {
    const int orow0 = row0 + wr * 64 + (lane >> 4) * 4;
    const int ocol0 = wc * 64 + lrow;
    #pragma unroll
    for (int fm = 0; fm < 4; ++fm)
      #pragma unroll
      for (int fn = 0; fn < 4; ++fn)
        #pragma unroll
        for (int r = 0; r < 4; ++r)
          out[(size_t)(orow0 + fm * 16 + r) * OUT_F + ocol0 + fn * 16] = acc[fm][fn][r];
  }
}

extern "C" void kernel_launch(void* const* d_in, const int* in_sizes, int n_in,
                              void* d_out, int out_size, void* d_ws, size_t ws_size,
                              hipStream_t stream) {
  const float* x      = (const float*)d_in[0];
  const float* gamma  = (const float*)d_in[1];
  const float* beta   = (const float*)d_in[2];
  const float* coeff  = (const float*)d_in[3];
  const float* base_w = (const float*)d_in[4];
  float* out = (float*)d_out;
  _Float16* W2F = (_Float16*)d_ws;   // 1.5 MB workspace, chunk-frag-order

  prep_w<<<dim3(384), dim3(256), 0, stream>>>(coeff, base_w, W2F);
  kan_fused<<<dim3(32768 / BM), dim3(1024), 0, stream>>>(x, gamma, beta, W2F, out);
}

// Round 29
// 70.512 us; speedup vs baseline: 1.0044x; 1.0044x over previous
//
#include <hip/hip_runtime.h>
#include <hip/hip_bf16.h>

typedef _Float16 f16x8 __attribute__((ext_vector_type(8)));
typedef float f32x4 __attribute__((ext_vector_type(4)));

#define BM 128      // rows per block
#define NCHUNK 32   // 3072 / 96 ; chunk = 8 features = 96 K-halves
#define IN_F 256
#define OUT_F 256
#define KDIM 3072   // 256 * 12
// frag-order: one "group" = 512 halves = 64 lanes x 8 halves (1 KB)
// A (LDS dbuf): 24 groups ; B (LDS dbuf): 48 groups
// W2F global layout = chunk-major frag order: chunk c -> 48 contiguous groups
// waves 0..7: producers (stageB + produce). waves 8..15: consumers (MFMA, prio-boosted).

__device__ inline void async_b16(const void* g, void* l) {
  __builtin_amdgcn_global_load_lds(
      (const __attribute__((address_space(1))) unsigned int*)g,
      (__attribute__((address_space(3))) unsigned int*)l, 16, 0, 0);
}

static __device__ inline unsigned pack2(float a, float b) {
  union { _Float16 h[2]; unsigned u; } t;
  t.h[0] = (_Float16)a;
  t.h[1] = (_Float16)b;
  return t.u;
}

// W2F unit u (16B = 8 halves): c=u/3072, r=u%3072, bcb=r/192, r2=r%192,
// g=r2/64, lane=r2%64 ; col o = bcb*16+(lane&15), k8 = g*4+(lane>>4),
// k-halves = c*96 + k8*8 .. +7 ; k=i*12+m -> m<11: coeff[o][i][m], m==11: base_w[o][i]
__global__ __launch_bounds__(256) void prep_w(const float* __restrict__ coeff,
                                              const float* __restrict__ base_w,
                                              _Float16* __restrict__ W2F) {
  const int u   = blockIdx.x * 256 + threadIdx.x;   // 384*256 = 98304 units
  const int c   = u / 3072;
  const int r   = u % 3072;
  const int bcb = r / 192;
  const int r2  = r % 192;
  const int g   = r2 / 64;
  const int ln  = r2 % 64;
  const int o   = bcb * 16 + (ln & 15);
  const int k8  = g * 4 + (ln >> 4);
  const int kh0 = c * 96 + k8 * 8;
  _Float16 h[8];
  #pragma unroll
  for (int e = 0; e < 8; ++e) {
    const int k = kh0 + e;
    const int i = k / 12, m = k % 12;
    const float v = (m == 11) ? base_w[o * IN_F + i] : coeff[(o * IN_F + i) * 11 + m];
    h[e] = (_Float16)v;
  }
  *(f16x8*)&W2F[(size_t)u * 8] = *(const f16x8*)h;
}

__global__ __launch_bounds__(1024, 4) void kan_fused(const float* __restrict__ x,
                                                     const float* __restrict__ gamma,
                                                     const float* __restrict__ beta,
                                                     const _Float16* __restrict__ W2F,
                                                     float* __restrict__ out) {
  __shared__ _Float16 A0[24 * 512], A1[24 * 512];   // 24 KB each
  __shared__ _Float16 B0[48 * 512], B1[48 * 512];   // 48 KB each
  __shared__ float mu_s[BM], rs_s[BM];

  const int tid  = threadIdx.x;
  const int lane = tid & 63;
  const int wid  = tid >> 6;          // 0..15
  const int row0 = blockIdx.x * BM;

  const bool isprod = (wid < 8);

  // consumer roles (waves 8..15): wr = row half, wc = col group; 64x64 tiles
  const int wr   = (wid >> 2) & 1;
  const int wc   = wid & 3;
  const int lrow = lane & 15;

  f32x4 acc[4][4] = {};

  // producer map (waves 0..7):
  const int plrow = tid & 15;
  const int pfq   = (tid >> 4) & 3;   // feature-pair within chunk
  const int prb   = (tid >> 6) & 7;   // row block 0..7
  const int prow  = prb * 16 + plrow; // 0..127
  const float* xrow = x + (size_t)(row0 + prow) * IN_F + pfq * 2;
  const float* grow = gamma + pfq * 2;
  const float* brow = beta + pfq * 2;

  // producer dest offsets (halves), one per 8-half group k8 = pfq*3 + j
  int aoff0, aoff1, aoff2;
  {
    const int k80 = pfq * 3 + 0, k81 = pfq * 3 + 1, k82 = pfq * 3 + 2;
    aoff0 = (prb * 3 + (k80 >> 2)) * 512 + (k80 & 3) * 128 + plrow * 8;
    aoff1 = (prb * 3 + (k81 >> 2)) * 512 + (k81 & 3) * 128 + plrow * 8;
    aoff2 = (prb * 3 + (k82 >> 2)) * 512 + (k82 & 3) * 128 + plrow * 8;
  }

  // B staging via async DMA: producer wave w stages groups w*6 .. w*6+5
  const char* const wsrc = (const char*)W2F + (size_t)(wid & 7) * 6144 + (size_t)lane * 16;
  auto stageB = [&](int c, _Float16* Bb) {
    const char* gb = wsrc + (size_t)c * 49152;
    char* lb = (char*)Bb + (wid & 7) * 6144;
    #pragma unroll
    for (int j = 0; j < 6; ++j)
      async_b16(gb + j * 1024, lb + j * 1024);
  };

  // ---- prologue part 1 (T14 issue-early): producers launch DMA + prefetch
  float2 xv0 = {}, gv0 = {}, bv0 = {}, xv1 = {}, gv1 = {}, bv1 = {};
  if (isprod) {
    stageB(0, B0);                    // DMA latency hides under the LN pass
    xv0 = *(const float2*)(xrow);
    gv0 = *(const float2*)(grow);
    bv0 = *(const float2*)(brow);
    xv1 = *(const float2*)(xrow + 8);
    gv1 = *(const float2*)(grow + 8);
    bv1 = *(const float2*)(brow + 8);
  }

  // ---- LN stats, 8 lanes per row (parallel): all 128 rows in one pass ----
  {
    const int g  = lane >> 3;         // row group within wave: 0..7
    const int sl = lane & 7;          // sub-lane within row
    const int rr = wid * 8 + g;       // 0..127
    const float* rp = x + (size_t)(row0 + rr) * IN_F + sl * 4;
    float s = 0.0f, sq = 0.0f;
    #pragma unroll
    for (int j = 0; j < 8; ++j) {     // 8 independent float4 loads
      const float4 v = *(const float4*)(rp + j * 32);
      s  += v.x + v.y + v.z + v.w;
      sq += v.x * v.x + v.y * v.y + v.z * v.z + v.w * v.w;
    }
    #pragma unroll
    for (int off = 4; off >= 1; off >>= 1) {
      s  += __shfl_xor(s, off);
      sq += __shfl_xor(sq, off);
    }
    if (sl == 0) {
      const float mu  = s * (1.0f / 256.0f);
      const float var = sq * (1.0f / 256.0f) - mu * mu;
      mu_s[rr] = mu;
      rs_s[rr] = 1.0f / sqrtf(var + 1e-5f);
    }
  }
  __syncthreads();                    // stats visible + B(0) DMA drained

  float mu = 0.0f, rs = 0.0f;
  if (isprod) { mu = mu_s[prow]; rs = rs_s[prow]; }

  // two-stage register window-placement produce
  auto produce = [&](_Float16* buf, float2 xv, float2 gv, float2 bv) {
    unsigned R[12];
    #pragma unroll
    for (int q = 0; q < 2; ++q) {
      const float xr = q ? xv.y : xv.x;
      const float gq = q ? gv.y : gv.x;
      const float bq = q ? bv.y : bv.x;
      const float n  = (xr - mu) * rs * gq + bq;
      const float v  = (n + 1.75f) * 4.0f;      // knots t_j = -1.75 + 0.25*j
      const float fj = floorf(v);
      const float u  = v - fj;
      const float u2 = u * u, u3 = u2 * u;
      const float w0 = (1.0f / 6.0f) * (1.0f - 3.0f * u + 3.0f * u2 - u3);
      const float w1 = (1.0f / 6.0f) * (3.0f * u3 - 6.0f * u2 + 4.0f);
      const float w2 = (1.0f / 6.0f) * (-3.0f * u3 + 3.0f * u2 + 3.0f * u + 1.0f);
      const float w3 = (1.0f / 6.0f) * u3;
      const unsigned W0 = pack2(w0, w1);
      const unsigned W1 = pack2(w2, w3);
      const int p    = (int)fj - 3;             // window start half
      const bool odd = (p & 1);
      const unsigned v0 = odd ? (W0 << 16) : W0;
      const unsigned v1 = odd ? ((W0 >> 16) | (W1 << 16)) : W1;
      const unsigned v2 = odd ? (W1 >> 16) : 0u;
      const int s0 = (v >= 0.0f && v < 14.0f) ? (p >> 1) : 99;  // OOB -> all drop
      const int s1 = s0 + 1, s2 = s0 + 2;
      #pragma unroll
      for (int k = 0; k < 6; ++k) {
        unsigned r = (k == s0) ? v0 : 0u;
        r = (k == s1) ? v1 : r;
        r = (k == s2) ? v2 : r;
        R[q * 6 + k] = r;
      }
      const float sl2 = xr * __builtin_amdgcn_rcpf(1.0f + __expf(-xr));  // silu(raw x)
      // half 11 of the field = word 5 high half (also kills j=12/13 overhang)
      R[q * 6 + 5] = (R[q * 6 + 5] & 0x0000FFFFu) | pack2(0.0f, sl2);
    }
    *(f16x8*)&buf[aoff0] = *(const f16x8*)&R[0];
    *(f16x8*)&buf[aoff1] = *(const f16x8*)&R[4];
    *(f16x8*)&buf[aoff2] = *(const f16x8*)&R[8];
  };

  auto domfma = [&](const _Float16* Ab, const _Float16* Bb) {
    __builtin_amdgcn_s_setprio(1);    // T5: consumer MFMA waves win issue arbitration
    #pragma unroll
    for (int fk = 0; fk < 3; ++fk) {
      f16x8 a[4], b[4];
      #pragma unroll
      for (int fm = 0; fm < 4; ++fm)
        a[fm] = *(const f16x8*)&Ab[((wr * 4 + fm) * 3 + fk) * 512 + lane * 8];
      #pragma unroll
      for (int fn = 0; fn < 4; ++fn)
        b[fn] = *(const f16x8*)&Bb[((wc * 4 + fn) * 3 + fk) * 512 + lane * 8];
      #pragma unroll
      for (int fm = 0; fm < 4; ++fm)
        #pragma unroll
        for (int fn = 0; fn < 4; ++fn)
          acc[fm][fn] = __builtin_amdgcn_mfma_f32_16x16x32_f16(a[fm], b[fn], acc[fm][fn], 0, 0, 0);
    }
    __builtin_amdgcn_s_setprio(0);
  };

  // prologue part 2: produce A(0)
  if (isprod) produce(A0, xv0, gv0, bv0);
  __syncthreads();                    // A(0) visible

  for (int c = 0; c < NCHUNK; c += 2) {
    const int cp2 = (c + 2 < NCHUNK) ? (c + 2) : (NCHUNK - 1);
    const int cp3 = (c + 3 < NCHUNK) ? (c + 3) : (NCHUNK - 1);
    // interval even: consumers eat {A0,B0}=c ; producers build {A1,B1}=c+1
    if (isprod) {
      stageB(c + 1, B1);
      xv0 = *(const float2*)(xrow + cp2 * 8);
      gv0 = *(const float2*)(grow + cp2 * 8);
      bv0 = *(const float2*)(brow + cp2 * 8);
      produce(A1, xv1, gv1, bv1);
    } else {
      domfma(A0, B0);
    }
    __syncthreads();
    // interval odd: consumers eat {A1,B1}=c+1 ; producers build {A0,B0}=c+2
    if (isprod) {
      if (c + 2 < NCHUNK) {
        stageB(cp2, B0);
        xv1 = *(const float2*)(xrow + cp3 * 8);
        gv1 = *(const float2*)(grow + cp3 * 8);
        bv1 = *(const float2*)(brow + cp3 * 8);
        produce(A0, xv0, gv0, bv0);
      }
    } else {
      domfma(A1, B1);
    }
    __syncthreads();
  }

  // ---- epilogue (consumers only): col = lane&15, row = (lane>>4)*4 + r ----
  if (!isprod) {
    const int orow0 = row0 + wr * 64 + (lane >> 4) * 4;
    const int ocol0 = wc * 64 + lrow;
    #pragma unroll
    for (int fm = 0; fm < 4; ++fm)
      #pragma unroll
      for (int fn = 0; fn < 4; ++fn)
        #pragma unroll
        for (int r = 0; r < 4; ++r)
          out[(size_t)(orow0 + fm * 16 + r) * OUT_F + ocol0 + fn * 16] = acc[fm][fn][r];
  }
}

extern "C" void kernel_launch(void* const* d_in, const int* in_sizes, int n_in,
                              void* d_out, int out_size, void* d_ws, size_t ws_size,
                              hipStream_t stream) {
  const float* x      = (const float*)d_in[0];
  const float* gamma  = (const float*)d_in[1];
  const float* beta   = (const float*)d_in[2];
  const float* coeff  = (const float*)d_in[3];
  const float* base_w = (const float*)d_in[4];
  float* out = (float*)d_out;
  _Float16* W2F = (_Float16*)d_ws;   // 1.5 MB workspace, chunk-frag-order

  prep_w<<<dim3(384), dim3(256), 0, stream>>>(coeff, base_w, W2F);
  kan_fused<<<dim3(32768 / BM), dim3(1024), 0, stream>>>(x, gamma, beta, W2F, out);
}